// Round 1
// baseline (130.980 us; speedup 1.0000x reference)
//
#include <hip/hip_runtime.h>
#include <hip/hip_bf16.h>

#define BB 2
#define DD 160
#define HH 192
#define WW 160

// total voxels = 2*160*192*160 = 9,830,400 ; /4 = 2,457,600 threads

__device__ __forceinline__ float interp_one(const float* __restrict__ vb,
                                            float ld, float lh, float lw) {
    // clamp to domain (matches jnp.clip(loc, 0, dim-1))
    ld = fminf(fmaxf(ld, 0.0f), (float)(DD - 1));
    lh = fminf(fmaxf(lh, 0.0f), (float)(HH - 1));
    lw = fminf(fmaxf(lw, 0.0f), (float)(WW - 1));

    float fd0 = floorf(ld), fh0 = floorf(lh), fw0 = floorf(lw);
    float td = ld - fd0, th = lh - fh0, tw = lw - fw0;

    int d0 = (int)fd0, h0 = (int)fh0, w0 = (int)fw0;
    int d1 = min(d0 + 1, DD - 1);
    int h1 = min(h0 + 1, HH - 1);
    int w1 = min(w0 + 1, WW - 1);

    const long sD = (long)HH * WW;
    const long sH = WW;

    const float* p00 = vb + (long)d0 * sD + (long)h0 * sH;
    const float* p01 = vb + (long)d0 * sD + (long)h1 * sH;
    const float* p10 = vb + (long)d1 * sD + (long)h0 * sH;
    const float* p11 = vb + (long)d1 * sD + (long)h1 * sH;

    float v000 = p00[w0], v001 = p00[w1];
    float v010 = p01[w0], v011 = p01[w1];
    float v100 = p10[w0], v101 = p10[w1];
    float v110 = p11[w0], v111 = p11[w1];

    // lerp along w, then h, then d
    float x00 = v000 + tw * (v001 - v000);
    float x01 = v010 + tw * (v011 - v010);
    float x10 = v100 + tw * (v101 - v100);
    float x11 = v110 + tw * (v111 - v110);

    float y0 = x00 + th * (x01 - x00);
    float y1 = x10 + th * (x11 - x10);

    return y0 + td * (y1 - y0);
}

__global__ void __launch_bounds__(256)
st_trilinear_kernel(const float* __restrict__ vol,
                    const float* __restrict__ shift,
                    float* __restrict__ out, int total4) {
    int t = blockIdx.x * blockDim.x + threadIdx.x;
    if (t >= total4) return;

    long base = (long)t * 4;   // first of 4 consecutive voxels (same row: W%4==0)
    int w = (int)(base % WW);
    long rest = base / WW;
    int h = (int)(rest % HH);
    rest /= HH;
    int d = (int)(rest % DD);
    int b = (int)(rest / DD);

    const float* vb = vol + (long)b * DD * HH * WW;

    // loc_shift: [..., 3] -> 12 consecutive floats for 4 voxels, 16B-aligned
    const float4* sp = reinterpret_cast<const float4*>(shift + base * 3);
    float4 s0 = sp[0];
    float4 s1 = sp[1];
    float4 s2 = sp[2];
    // voxel j components (d,h,w): floats [3j, 3j+1, 3j+2]
    float sd[4] = { s0.x, s0.w, s1.z, s2.y };
    float sh[4] = { s0.y, s1.x, s1.w, s2.z };
    float sw[4] = { s0.z, s1.y, s2.x, s2.w };

    float4 o;
    o.x = interp_one(vb, (float)d + sd[0], (float)h + sh[0], (float)(w + 0) + sw[0]);
    o.y = interp_one(vb, (float)d + sd[1], (float)h + sh[1], (float)(w + 1) + sw[1]);
    o.z = interp_one(vb, (float)d + sd[2], (float)h + sh[2], (float)(w + 2) + sw[2]);
    o.w = interp_one(vb, (float)d + sd[3], (float)h + sh[3], (float)(w + 3) + sw[3]);

    *reinterpret_cast<float4*>(out + base) = o;
}

extern "C" void kernel_launch(void* const* d_in, const int* in_sizes, int n_in,
                              void* d_out, int out_size, void* d_ws, size_t ws_size,
                              hipStream_t stream) {
    const float* vol   = (const float*)d_in[0];
    const float* shift = (const float*)d_in[1];
    float* out = (float*)d_out;

    const int total  = BB * DD * HH * WW;  // 9,830,400
    const int total4 = total / 4;          // 2,457,600
    const int block  = 256;
    const int grid   = (total4 + block - 1) / block;  // 9600

    st_trilinear_kernel<<<grid, block, 0, stream>>>(vol, shift, out, total4);
}

// Round 2
// 81.048 us; speedup vs baseline: 1.6161x; 1.6161x over previous
//
#include <hip/hip_runtime.h>
#include <hip/hip_bf16.h>

#define BB 2
#define DD 160
#define HH 192
#define WW 160

// total voxels = 2*160*192*160 = 9,830,400 ; /4 = 2,457,600 threads

__device__ __forceinline__ float2 ld2(const float* p) {
    float2 v;
    __builtin_memcpy(&v, p, 8);   // emits global_load_dwordx2 (align-4 ok on gfx950)
    return v;
}

__device__ __forceinline__ float interp_one(const float* __restrict__ vb,
                                            float ld, float lh, float lw) {
    // clamp to domain (matches jnp.clip(loc, 0, dim-1))
    ld = fminf(fmaxf(ld, 0.0f), (float)(DD - 1));
    lh = fminf(fmaxf(lh, 0.0f), (float)(HH - 1));
    lw = fminf(fmaxf(lw, 0.0f), (float)(WW - 1));

    float fd0 = floorf(ld), fh0 = floorf(lh), fw0 = floorf(lw);
    float td = ld - fd0, th = lh - fh0;

    int d0 = (int)fd0, h0 = (int)fh0, w0 = (int)fw0;
    int d1 = min(d0 + 1, DD - 1);
    int h1 = min(h0 + 1, HH - 1);

    // pair-load trick: load (v[wp], v[wp+1]) with wp = min(w0, W-2); shift the
    // lerp weight by (w0-wp). For w0<=W-2 this is identical; for w0==W-1
    // (only possible when lw==W-1 exactly, so tw==0) weight becomes 1 and the
    // result is v[W-1]. Exact, and never reads past the row.
    int wp = min(w0, WW - 2);
    float tw = (lw - fw0) + (float)(w0 - wp);

    const int sD = HH * WW;
    const int sH = WW;
    int d1o = (d1 - d0) * sD;    // 0 or sD
    int h1o = (h1 - h0) * sH;    // 0 or sH

    const float* r00 = vb + d0 * sD + h0 * sH + wp;

    float2 a00 = ld2(r00);
    float2 a01 = ld2(r00 + h1o);
    float2 a10 = ld2(r00 + d1o);
    float2 a11 = ld2(r00 + d1o + h1o);

    float x00 = a00.x + tw * (a00.y - a00.x);
    float x01 = a01.x + tw * (a01.y - a01.x);
    float x10 = a10.x + tw * (a10.y - a10.x);
    float x11 = a11.x + tw * (a11.y - a11.x);

    float y0 = x00 + th * (x01 - x00);
    float y1 = x10 + th * (x11 - x10);

    return y0 + td * (y1 - y0);
}

__global__ void __launch_bounds__(256)
st_trilinear_kernel(const float* __restrict__ vol,
                    const float* __restrict__ shift,
                    float* __restrict__ out, int total4) {
    int t = blockIdx.x * blockDim.x + threadIdx.x;
    if (t >= total4) return;

    int base = t * 4;   // first of 4 consecutive voxels (same row: W%4==0)
    int w = base % WW;
    int rest = base / WW;
    int h = rest % HH;
    rest /= HH;
    int d = rest % DD;
    int b = rest / DD;

    const float* vb = vol + (long)b * (DD * HH * WW);

    // loc_shift: [..., 3] -> 12 consecutive floats for 4 voxels, 16B-aligned
    const float4* sp = reinterpret_cast<const float4*>(shift + (long)base * 3);
    float4 s0 = sp[0];
    float4 s1 = sp[1];
    float4 s2 = sp[2];
    // voxel j components (d,h,w): floats [3j, 3j+1, 3j+2]
    float sd[4] = { s0.x, s0.w, s1.z, s2.y };
    float sh[4] = { s0.y, s1.x, s1.w, s2.z };
    float sw[4] = { s0.z, s1.y, s2.x, s2.w };

    float4 o;
    o.x = interp_one(vb, (float)d + sd[0], (float)h + sh[0], (float)(w + 0) + sw[0]);
    o.y = interp_one(vb, (float)d + sd[1], (float)h + sh[1], (float)(w + 1) + sw[1]);
    o.z = interp_one(vb, (float)d + sd[2], (float)h + sh[2], (float)(w + 2) + sw[2]);
    o.w = interp_one(vb, (float)d + sd[3], (float)h + sh[3], (float)(w + 3) + sw[3]);

    *reinterpret_cast<float4*>(out + base) = o;
}

extern "C" void kernel_launch(void* const* d_in, const int* in_sizes, int n_in,
                              void* d_out, int out_size, void* d_ws, size_t ws_size,
                              hipStream_t stream) {
    const float* vol   = (const float*)d_in[0];
    const float* shift = (const float*)d_in[1];
    float* out = (float*)d_out;

    const int total  = BB * DD * HH * WW;  // 9,830,400
    const int total4 = total / 4;          // 2,457,600
    const int block  = 256;
    const int grid   = (total4 + block - 1) / block;  // 9600

    st_trilinear_kernel<<<grid, block, 0, stream>>>(vol, shift, out, total4);
}

// Round 3
// 57.788 us; speedup vs baseline: 2.2666x; 1.4025x over previous
//
#include <hip/hip_runtime.h>
#include <hip/hip_bf16.h>

#define BB 2
#define DD 160
#define HH 192
#define WW 160

// 3D-tiled mapping: block = 32(w) x 8(h) threads, each thread does 4 d-slices.
// Grid = (W/32, H/8, (D/4)*B) = (5, 24, 80). Wave = 2 h-rows x 32 w at one d
// -> compact gather neighborhood (~8.5 KB), reused across the 4 d iterations.

__device__ __forceinline__ float2 ld2(const float* p) {
    float2 v;
    __builtin_memcpy(&v, p, 8);   // global_load_dwordx2 (align-4 ok)
    return v;
}

__device__ __forceinline__ float interp_one(const float* __restrict__ vb,
                                            float ld, float lh, float lw) {
    // clamp to domain (matches jnp.clip(loc, 0, dim-1))
    ld = fminf(fmaxf(ld, 0.0f), (float)(DD - 1));
    lh = fminf(fmaxf(lh, 0.0f), (float)(HH - 1));
    lw = fminf(fmaxf(lw, 0.0f), (float)(WW - 1));

    float fd0 = floorf(ld), fh0 = floorf(lh), fw0 = floorf(lw);
    float td = ld - fd0, th = lh - fh0;

    int d0 = (int)fd0, h0 = (int)fh0, w0 = (int)fw0;
    int d1 = min(d0 + 1, DD - 1);
    int h1 = min(h0 + 1, HH - 1);

    // pair-load trick: load (v[wp], v[wp+1]) with wp = min(w0, W-2); shift the
    // lerp weight by (w0-wp). Exact (tw==0 when w0==W-1), never over-reads.
    int wp = min(w0, WW - 2);
    float tw = (lw - fw0) + (float)(w0 - wp);

    const int sD = HH * WW;
    const int sH = WW;
    int d1o = (d1 - d0) * sD;    // 0 or sD
    int h1o = (h1 - h0) * sH;    // 0 or sH

    const float* r00 = vb + d0 * sD + h0 * sH + wp;

    float2 a00 = ld2(r00);
    float2 a01 = ld2(r00 + h1o);
    float2 a10 = ld2(r00 + d1o);
    float2 a11 = ld2(r00 + d1o + h1o);

    float x00 = a00.x + tw * (a00.y - a00.x);
    float x01 = a01.x + tw * (a01.y - a01.x);
    float x10 = a10.x + tw * (a10.y - a10.x);
    float x11 = a11.x + tw * (a11.y - a11.x);

    float y0 = x00 + th * (x01 - x00);
    float y1 = x10 + th * (x11 - x10);

    return y0 + td * (y1 - y0);
}

__global__ void __launch_bounds__(256)
st_trilinear_tiled(const float* __restrict__ vol,
                   const float* __restrict__ shift,
                   float* __restrict__ out) {
    const int w = blockIdx.x * 32 + threadIdx.x;   // 0..159
    const int h = blockIdx.y * 8 + threadIdx.y;    // 0..191
    const int dz = blockIdx.z;                     // 0..79
    const int b  = dz >> 5 >= 0 ? dz / 40 : 0;     // 40 d-tiles per batch
    const int d0 = (dz % 40) * 4;

    const float* vb = vol + (long)b * (DD * HH * WW);
    const long sD = (long)HH * WW;
    long idx = (((long)b * DD + d0) * HH + h) * WW + w;

    const float fh = (float)h, fw = (float)w;

#pragma unroll
    for (int j = 0; j < 4; ++j) {
        long id = idx + (long)j * sD;
        float3 s;
        __builtin_memcpy(&s, shift + id * 3, 12);   // dwordx3, coalesced
        float r = interp_one(vb, (float)(d0 + j) + s.x, fh + s.y, fw + s.z);
        __builtin_nontemporal_store(r, out + id);
    }
}

extern "C" void kernel_launch(void* const* d_in, const int* in_sizes, int n_in,
                              void* d_out, int out_size, void* d_ws, size_t ws_size,
                              hipStream_t stream) {
    const float* vol   = (const float*)d_in[0];
    const float* shift = (const float*)d_in[1];
    float* out = (float*)d_out;

    dim3 block(32, 8, 1);
    dim3 grid(WW / 32, HH / 8, (DD / 4) * BB);   // (5, 24, 80)

    st_trilinear_tiled<<<grid, block, 0, stream>>>(vol, shift, out);
}